// Round 1
// baseline (115.306 us; speedup 1.0000x reference)
//
#include <hip/hip_runtime.h>

// CMDNet_58274116272706 — B=16384, NR=64, NT=32, M=4, NITER=64.
// Phase 1: HH = Ht^T Ht per batch via f16 MFMA (Gram trick: A-frag == B-frag),
//          yH = y^T Ht in f32 VALU. Phase 2: 64 gradient steps, lane = nt,
//          4 M-slots/lane, HH column in registers, xt broadcast via tiny LDS.

#define NRr 64
#define NTt 32
#define NITER 64
#define B_TOTAL 16384

using f16x8  = __attribute__((ext_vector_type(8))) _Float16;
using f32x16 = __attribute__((ext_vector_type(16))) float;

__global__ __launch_bounds__(256) void cmdnet_kernel(
    const float* __restrict__ yt,     // [B,64]
    const float* __restrict__ Ht,     // [B,64,32]
    const float* __restrict__ sig0,   // [B]
    const float* __restrict__ mm,     // [4]
    const float* __restrict__ alpha,  // [4]
    const float* __restrict__ taui,   // [65]
    const float* __restrict__ delta,  // [64]
    float* __restrict__ out)          // ft [B,32,4] then xt [B,32]
{
    __shared__ float xts[4][2][32];           // per-wave xt broadcast buffer

    const int tid = threadIdx.x;
    const int w   = tid >> 6;                 // wave in block (0..3)
    const int l   = tid & 63;                 // lane
    const int j   = l & 31;                   // nt / matrix column
    const int hi  = l >> 5;                   // half-wave id
    const int b0  = (blockIdx.x * 4 + w) * 2; // first of this wave's 2 batches

    // ---------------- Phase 1: HH (MFMA f16) + yH (f32) for b0, b0+1 -------
    f32x16 accA = {}, accB = {};
    float  ypA = 0.f, ypB = 0.f;
#pragma unroll
    for (int bb = 0; bb < 2; ++bb) {
        const int b = b0 + bb;
        const float* hp = Ht + (size_t)b * NRr * NTt + j;
        const float* yp = yt + (size_t)b * NRr;
        f32x16 acc = {};
        float  ypart = 0.f;
#pragma unroll
        for (int kc = 0; kc < 4; ++kc) {
            const int kb = kc * 16 + hi * 8;  // this lane's 8 k values
            float h[8];
#pragma unroll
            for (int e = 0; e < 8; ++e) h[e] = hp[(size_t)(kb + e) * NTt];
            const float4 ya = *(const float4*)(yp + kb);
            const float4 yb = *(const float4*)(yp + kb + 4);
            ypart += h[0]*ya.x + h[1]*ya.y + h[2]*ya.z + h[3]*ya.w
                   + h[4]*yb.x + h[5]*yb.y + h[6]*yb.z + h[7]*yb.w;
            f16x8 fa;
#pragma unroll
            for (int e = 0; e < 8; ++e) fa[e] = (_Float16)h[e];
            // A[i][k]=Ht[k][i], B[k][j]=Ht[k][j]: identical fragment (Gram).
            acc = __builtin_amdgcn_mfma_f32_32x32x16_f16(fa, fa, acc, 0, 0, 0);
        }
        if (bb == 0) { accA = acc; ypA = ypart; }
        else         { accB = acc; ypB = ypart; }
    }

    // Redistribute: lane (j,hi) gets full column j of HH for batch b0+hi.
    // C/D layout: col = lane&31, row = (reg&3) + 8*(reg>>2) + 4*(lane>>5).
    float hh[32];
#pragma unroll
    for (int r = 0; r < 16; ++r) {
        const float own = hi ? accB[r] : accA[r];  // my batch, my rows
        const float snd = hi ? accA[r] : accB[r];  // other half's batch -> send
        const float oth = __shfl_xor(snd, 32, 64); // my batch, other rows
        const int g = r >> 2, k = r & 3;
        hh[8*g + k]     = hi ? oth : own;          // rows 8g+k   (h2=0)
        hh[8*g + 4 + k] = hi ? own : oth;          // rows 8g+4+k (h2=1)
    }
    const float yA = ypA + __shfl_xor(ypA, 32, 64);
    const float yB = ypB + __shfl_xor(ypB, 32, 64);
    const float yH = hi ? yB : yA;

    const int   bmy  = b0 + hi;
    const float sgv  = sig0[bmy];
    const float sig2 = sgv * sgv;

    const float4 mv = *(const float4*)mm;
    const float4 av = *(const float4*)alpha;
    const float m0 = mv.x, m1 = mv.y, m2 = mv.z, m3 = mv.w;
    const float la0 = __logf(av.x), la1 = __logf(av.y),
                la2 = __logf(av.z), la3 = __logf(av.w);

    // ---------------- Phase 2: 64 descent steps ----------------------------
    float G0 = 0.f, G1 = 0.f, G2 = 0.f, G3 = 0.f;

    for (int it = 0; it < NITER; ++it) {
        const float ta = fabsf(taui[it]);
        const float sc = (it == 0) ? 1.0f : ta;   // ft_scale[0] = 1
        const float d  = delta[it];

        // softmax((la + G) * sc) over M=4, max-subtracted like jax
        const float s0 = (la0 + G0) * sc, s1 = (la1 + G1) * sc;
        const float s2 = (la2 + G2) * sc, s3 = (la3 + G3) * sc;
        const float mx = fmaxf(fmaxf(s0, s1), fmaxf(s2, s3));
        const float e0 = __expf(s0 - mx), e1 = __expf(s1 - mx);
        const float e2 = __expf(s2 - mx), e3 = __expf(s3 - mx);
        const float Z  = (e0 + e1) + (e2 + e3);
        const float R  = __builtin_amdgcn_rcpf(Z);
        const float ft0 = e0 * R, ft1 = e1 * R, ft2 = e2 * R, ft3 = e3 * R;
        const float xt  = (ft0*m0 + ft1*m1) + (ft2*m2 + ft3*m3);

        // broadcast xt within half-wave via LDS (same-wave DS is in-order)
        xts[w][hi][j] = xt;
        asm volatile("" ::: "memory");
        float acc = 0.f;
        const float4* xv = (const float4*)&xts[w][hi][0];
#pragma unroll
        for (int q = 0; q < 8; ++q) {
            const float4 x4 = xv[q];
            acc += hh[4*q+0]*x4.x + hh[4*q+1]*x4.y
                 + hh[4*q+2]*x4.z + hh[4*q+3]*x4.w;
        }
        asm volatile("" ::: "memory");

        const float qd  = acc - yH;        // xHH - yH
        const float tqd = ta * qd * d;     // fold ta and delta
        const float ds2 = d * sig2;
        G0 -= ds2 * (1.f - __expf(-G0)) + tqd * (ft0 * (m0 - xt));
        G1 -= ds2 * (1.f - __expf(-G1)) + tqd * (ft1 * (m1 - xt));
        G2 -= ds2 * (1.f - __expf(-G2)) + tqd * (ft2 * (m2 - xt));
        G3 -= ds2 * (1.f - __expf(-G3)) + tqd * (ft3 * (m3 - xt));
    }

    // ---------------- Final layer: softmax + soft symbol, store ------------
    {
        const float ta = fabsf(taui[NITER]);
        const float s0 = (la0 + G0) * ta, s1 = (la1 + G1) * ta;
        const float s2 = (la2 + G2) * ta, s3 = (la3 + G3) * ta;
        const float mx = fmaxf(fmaxf(s0, s1), fmaxf(s2, s3));
        const float e0 = __expf(s0 - mx), e1 = __expf(s1 - mx);
        const float e2 = __expf(s2 - mx), e3 = __expf(s3 - mx);
        const float Z  = (e0 + e1) + (e2 + e3);
        const float R  = __builtin_amdgcn_rcpf(Z);
        const float ft0 = e0 * R, ft1 = e1 * R, ft2 = e2 * R, ft3 = e3 * R;
        const float xt  = (ft0*m0 + ft1*m1) + (ft2*m2 + ft3*m3);

        float4 f4; f4.x = ft0; f4.y = ft1; f4.z = ft2; f4.w = ft3;
        *(float4*)(out + ((size_t)bmy * NTt + j) * 4) = f4;
        out[(size_t)B_TOTAL * NTt * 4 + (size_t)bmy * NTt + j] = xt;
    }
}

extern "C" void kernel_launch(void* const* d_in, const int* in_sizes, int n_in,
                              void* d_out, int out_size, void* d_ws, size_t ws_size,
                              hipStream_t stream) {
    const float* yt    = (const float*)d_in[0];
    const float* Ht    = (const float*)d_in[1];
    const float* sig0  = (const float*)d_in[2];
    const float* mm    = (const float*)d_in[3];
    const float* alpha = (const float*)d_in[4];
    const float* taui  = (const float*)d_in[5];
    const float* delta = (const float*)d_in[6];
    float* out = (float*)d_out;

    const int blocks = B_TOTAL / 8;   // 8 batches per 256-thread block
    cmdnet_kernel<<<blocks, 256, 0, stream>>>(yt, Ht, sig0, mm, alpha, taui,
                                              delta, out);
}